// Round 6
// baseline (205.855 us; speedup 1.0000x reference)
//
#include <hip/hip_runtime.h>
#include <cstdint>
#include <cstddef>

using u16 = unsigned short;
typedef short short8 __attribute__((ext_vector_type(8)));
typedef __bf16 bf16x8 __attribute__((ext_vector_type(8)));
typedef float f32x4 __attribute__((ext_vector_type(4)));
typedef u16 u16x4 __attribute__((ext_vector_type(4)));

__device__ __forceinline__ u16 f2bf(float f) {
  union { float f; uint32_t u; } v; v.f = f;
  uint32_t r = v.u + 0x7FFF + ((v.u >> 16) & 1);
  return (u16)(r >> 16);
}
__device__ __forceinline__ float bf2f(u16 b) {
  union { uint32_t u; float f; } v; v.u = ((uint32_t)b) << 16;
  return v.f;
}

__device__ __forceinline__ void gload16(const u16* g, u16* l) {
  __builtin_amdgcn_global_load_lds(
      (const __attribute__((address_space(1))) void*)g,
      (__attribute__((address_space(3))) void*)l, 16, 0, 0);
}

// =====================================================================
// R6: 256x256 bf16 GEMM, BK=64, 8 waves (2x4).
//  - B DIRECT FROM GLOBAL (L2-hot, W=2MB fits per-XCD L2): no B staging,
//    no B LDS reads. 8 global_load_dwordx4 per wave per tile, one tile ahead.
//  - A only in LDS: 4 buffers x 32KB, staged 3 tiles ahead (gload_lds).
//  - ONE barrier per K-tile; all waits counted (queue ledger in comments).
//  - K-loop fully unrolled: all addresses fold to base+imm.
// Steady tile queue: enter [G(t)(8), S(t+2)(4)] -> vmcnt(4) gates bb;
// issue G(t+1)(8), S(t+3)(4) -> vmcnt(12) retires S(t+2) -> barrier.
// =====================================================================
template <int EPI>
__global__ __launch_bounds__(512, 2) void gemm_bdir(
    const u16* __restrict__ A, const u16* __restrict__ Bt,
    const float* __restrict__ bias,
    u16* __restrict__ Cb, float* __restrict__ Cf)
{
  constexpr int K = 1024, N = 1024, NT = 16;
  __shared__ alignas(16) u16 lds[65536];  // 4 bufs x 256x64 u16 = 128 KiB

  const int t = (int)threadIdx.x;
  const int lane = t & 63, wid = t >> 6;
  const int wr = wid >> 2, wc = wid & 3;   // 2 x 4 wave grid
  const int li = lane & 15, hk = lane >> 4;

  // bijective XCD swizzle (grid = 256, 8 XCDs, 32 blocks each)
  const int orig = (int)blockIdx.x;
  const int swz = (orig & 7) * 32 + (orig >> 3);
  const int bm = swz >> 2, bn = swz & 3;
  const int arow0 = bm * 256, brow0 = bn * 256;

  // A staging: 4 loads/thread/tile; load l covers rows wid*32+l*8 .. +8
  const int Rl = lane >> 3;
  const int sc8 = ((lane & 7) ^ Rl) << 3;  // source chunk XOR row&7 (row&7==Rl)

  // ds_read swizzled chunk offsets (u16 units); row&7 == li&7 for all frags
  int c8[2];
#pragma unroll
  for (int kk = 0; kk < 2; ++kk) c8[kk] = (((kk << 2) + hk) ^ (li & 7)) << 3;

  // B row base pointers (global); col = kt + kk*32 + hk*8
  const u16* bp[4];
#pragma unroll
  for (int n = 0; n < 4; ++n)
    bp[n] = Bt + (size_t)(brow0 + wc * 64 + n * 16 + li) * K + hk * 8;

  // A stage source bases (per l); col = sigma*64 + sc8
  const u16* ap[4];
#pragma unroll
  for (int l = 0; l < 4; ++l)
    ap[l] = A + (size_t)(arow0 + wid * 32 + l * 8 + Rl) * K + sc8;

  f32x4 acc[8][4];
#pragma unroll
  for (int m = 0; m < 8; ++m)
#pragma unroll
    for (int n = 0; n < 4; ++n)
#pragma unroll
      for (int j = 0; j < 4; ++j) acc[m][n][j] = 0.0f;

  short8 aa[8][2], bb[4][2];

  auto STAGE = [&](int sigma) {  // A(sigma) -> buf sigma%4  [4 gload_lds]
    const int ldsoff = (sigma & 3) * 16384 + wid * 2048;
#pragma unroll
    for (int l = 0; l < 4; ++l)
      gload16(ap[l] + sigma * 64, (u16*)lds + ldsoff + l * 512);
  };
  auto GLOADB = [&](int kt) {    // bb(kt/64) -> regs  [8 global_load_dwordx4]
#pragma unroll
    for (int n = 0; n < 4; ++n)
#pragma unroll
      for (int kk = 0; kk < 2; ++kk)
        bb[n][kk] = *reinterpret_cast<const short8*>(bp[n] + kt + kk * 32);
  };
  auto READA = [&](int tile) {   // aa(tile) from buf tile%4  [16 ds_read_b128]
    const int base = (tile & 3) * 16384 + wr * 8192 + li * 64;
#pragma unroll
    for (int m = 0; m < 8; ++m)
#pragma unroll
      for (int kk = 0; kk < 2; ++kk)
        aa[m][kk] = *reinterpret_cast<const short8*>(
            (const u16*)lds + base + m * 1024 + c8[kk]);
  };

  // ---- prologue: queue [S0(4),S1(4),S2(4),G0(8)]=20; vmcnt(8) => S0..S2 landed
  STAGE(0); STAGE(1); STAGE(2);
  GLOADB(0);
  asm volatile("s_waitcnt vmcnt(8)" ::: "memory");
  __builtin_amdgcn_sched_barrier(0);
  __builtin_amdgcn_s_barrier();   // publish buf0..buf2
  READA(0);

#pragma unroll
  for (int tau = 0; tau < NT; ++tau) {
    // gate bb(tau); leave S(tau+2) (if it exists) in flight
    if (tau >= 1 && tau + 2 < NT) {
      asm volatile("s_waitcnt vmcnt(4)" ::: "memory");
    } else {
      asm volatile("s_waitcnt vmcnt(0)" ::: "memory");
    }
    asm volatile("s_waitcnt lgkmcnt(0)" ::: "memory");  // aa(tau) landed
    __builtin_amdgcn_sched_barrier(0);
    __builtin_amdgcn_s_setprio(1);
#pragma unroll
    for (int m = 0; m < 8; ++m)
#pragma unroll
      for (int n = 0; n < 4; ++n)
#pragma unroll
        for (int kk = 0; kk < 2; ++kk)
          acc[m][n] = __builtin_amdgcn_mfma_f32_16x16x32_bf16(
              __builtin_bit_cast(bf16x8, aa[m][kk]),
              __builtin_bit_cast(bf16x8, bb[n][kk]),
              acc[m][n], 0, 0, 0);
    __builtin_amdgcn_s_setprio(0);
    __builtin_amdgcn_sched_barrier(0);

    if (tau + 1 < NT) GLOADB((tau + 1) * 64);   // [vm +8]
    if (tau + 3 < NT) STAGE(tau + 3);           // [vm +4] -> buf (tau+3)%4
    if (tau + 1 < NT) READA(tau + 1);           // [lgkm +16]

    if (tau + 2 < NT) {
      // gate S(tau+2) landed; leave G(tau+1) (+S(tau+3)) flying
      if (tau + 3 < NT) {
        asm volatile("s_waitcnt vmcnt(12)" ::: "memory");
      } else {
        asm volatile("s_waitcnt vmcnt(8)" ::: "memory");
      }
      __builtin_amdgcn_sched_barrier(0);
      __builtin_amdgcn_s_barrier();  // publish A(tau+2)
    }
  }

  // ---- epilogue
#pragma unroll
  for (int m = 0; m < 8; ++m) {
#pragma unroll
    for (int n = 0; n < 4; ++n) {
      const int gcol = brow0 + wc * 64 + n * 16 + li;
      const float bv = bias[gcol];
#pragma unroll
      for (int j = 0; j < 4; ++j) {
        const int grow = arow0 + wr * 128 + m * 16 + hk * 4 + j;
        float v = fmaxf(acc[m][n][j] + bv, 0.0f);
        if (EPI == 0) {
          Cb[(size_t)grow * N + gcol] = f2bf(v);
        } else {
          int tensor = grow >> 13, rr = grow & 8191;
          int tt = rr >> 3, b_ = rr & 7;
          Cf[(size_t)tensor * 8388608 + (size_t)b_ * 1048576 +
             (size_t)tt * 1024 + gcol] = v;
        }
      }
    }
  }
}

// =====================================================================
// 128x128 core (round-1, proven) — used by sim_kernel
// =====================================================================
__device__ __forceinline__ void gemm_core_128(
    const u16* __restrict__ A, const u16* __restrict__ B,
    int arow0, int brow0, int K,
    u16* As, u16* Bs, f32x4 (&acc)[4][4])
{
  const int t = (int)threadIdx.x;
  const int lane = t & 63, wv = t >> 6;
  const int wr = wv >> 1, wc = wv & 1;
  const int li = lane & 15, hk = lane >> 4;
  const int sr = t >> 3, sc = t & 7;

#pragma unroll
  for (int m = 0; m < 4; ++m)
#pragma unroll
    for (int n = 0; n < 4; ++n)
#pragma unroll
      for (int j = 0; j < 4; ++j) acc[m][n][j] = 0.0f;

  for (int kt = 0; kt < K; kt += 64) {
#pragma unroll
    for (int i = 0; i < 4; ++i) {
      int row = i * 32 + sr;
      int coff = (sc ^ (row & 7)) << 3;
      const u16* ga = A + (size_t)(arow0 + row) * K + kt + coff;
      const u16* gb = B + (size_t)(brow0 + row) * K + kt + coff;
      u16* la = As + i * 2048 + wv * 512;
      u16* lb = Bs + i * 2048 + wv * 512;
      gload16(ga, la);
      gload16(gb, lb);
    }
    __syncthreads();
#pragma unroll
    for (int kk = 0; kk < 2; ++kk) {
      short8 av[4], bv[4];
#pragma unroll
      for (int m = 0; m < 4; ++m) {
        int ra = wr * 64 + m * 16 + li;
        int ca = ((kk << 2) + hk) ^ (ra & 7);
        av[m] = *reinterpret_cast<const short8*>(As + ra * 64 + ca * 8);
      }
#pragma unroll
      for (int n = 0; n < 4; ++n) {
        int rb = wc * 64 + n * 16 + li;
        int cb = ((kk << 2) + hk) ^ (rb & 7);
        bv[n] = *reinterpret_cast<const short8*>(Bs + rb * 64 + cb * 8);
      }
#pragma unroll
      for (int m = 0; m < 4; ++m)
#pragma unroll
        for (int n = 0; n < 4; ++n)
          acc[m][n] = __builtin_amdgcn_mfma_f32_16x16x32_bf16(
              __builtin_bit_cast(bf16x8, av[m]),
              __builtin_bit_cast(bf16x8, bv[n]),
              acc[m][n], 0, 0, 0);
    }
    __syncthreads();
  }
}

// ---------------- similarity GEMM: S[m] += sum_col w[col]*exp(10*G[m][col]) ----------------
__global__ __launch_bounds__(256) void sim_kernel(const u16* __restrict__ Z,
                                                  float* __restrict__ S)
{
  __shared__ alignas(16) u16 As[128 * 64];
  __shared__ alignas(16) u16 Bs[128 * 64];
  const int bm = (int)blockIdx.x / 16, bn = (int)blockIdx.x % 16;
  f32x4 acc[4][4];
  gemm_core_128(Z, Z, bm * 128, bn * 128, 1024, As, Bs, acc);

  const int t = (int)threadIdx.x;
  const int lane = t & 63, wv = t >> 6;
  const int wr = wv >> 1, wc = wv & 1;
  const int li = lane & 15, hk = lane >> 4;

#pragma unroll
  for (int m = 0; m < 4; ++m) {
#pragma unroll
    for (int j = 0; j < 4; ++j) {
      int grow = bm * 128 + wr * 64 + m * 16 + hk * 4 + j;
      float s = 0.0f;
#pragma unroll
      for (int n = 0; n < 4; ++n) {
        int gcol = bn * 128 + wc * 64 + n * 16 + li;
        float logit = (grow == gcol) ? 10.0f : acc[m][n][j] * 10.0f;
        float w = (gcol == 0 || gcol == 1023 || gcol == 1024 || gcol == 2047)
                      ? 1.0f : 2.0f;
        s += w * expf(logit);
      }
      s += __shfl_xor(s, 1); s += __shfl_xor(s, 2);
      s += __shfl_xor(s, 4); s += __shfl_xor(s, 8);
      if (li == 0) atomicAdd(&S[grow], s);
    }
  }
}

// ---------------- small kernels ----------------
__global__ void convert_x(const float* __restrict__ h1,
                          const float* __restrict__ h2,
                          u16* __restrict__ Xb)
{
  size_t i4 = ((size_t)blockIdx.x * 256 + threadIdx.x) * 4;
  const float* src = (i4 < 8388608) ? (h1 + i4) : (h2 + (i4 - 8388608));
  float4 v = *reinterpret_cast<const float4*>(src);
  u16x4 o;
  o[0] = f2bf(v.x); o[1] = f2bf(v.y); o[2] = f2bf(v.z); o[3] = f2bf(v.w);
  *reinterpret_cast<u16x4*>(Xb + i4) = o;
}

__global__ void transpose_w(const float* __restrict__ W, u16* __restrict__ Wt)
{
  __shared__ float tile[32][33];
  const int bx = (int)blockIdx.x & 31, by = (int)blockIdx.x >> 5;
  const int tx = (int)threadIdx.x & 31, ty = (int)threadIdx.x >> 5;
#pragma unroll
  for (int i = 0; i < 4; ++i)
    tile[ty + i * 8][tx] = W[(size_t)(by * 32 + ty + i * 8) * 1024 + bx * 32 + tx];
  __syncthreads();
#pragma unroll
  for (int i = 0; i < 4; ++i)
    Wt[(size_t)(bx * 32 + ty + i * 8) * 1024 + by * 32 + tx] =
        f2bf(tile[tx][ty + i * 8]);
}

__global__ void row_normalize(const float* __restrict__ out, u16* __restrict__ Z)
{
  const int row = (int)blockIdx.x;   // 0..2047
  const int t = (int)threadIdx.x;    // 256
  const float* src = out + ((row < 1024)
      ? ((size_t)7 * 1048576 + (size_t)row * 1024)
      : ((size_t)8388608 + (size_t)7 * 1048576 + (size_t)(row - 1024) * 1024));
  float4 v = reinterpret_cast<const float4*>(src)[t];
  float ss = v.x * v.x + v.y * v.y + v.z * v.z + v.w * v.w;
#pragma unroll
  for (int d = 1; d < 64; d <<= 1) ss += __shfl_xor(ss, d);
  __shared__ float red[4];
  if ((t & 63) == 0) red[t >> 6] = ss;
  __syncthreads();
  float tot = red[0] + red[1] + red[2] + red[3];
  float inv = 1.0f / fmaxf(sqrtf(tot), 1e-12f);
  u16x4 o;
  o[0] = f2bf(v.x * inv); o[1] = f2bf(v.y * inv);
  o[2] = f2bf(v.z * inv); o[3] = f2bf(v.w * inv);
  reinterpret_cast<u16x4*>(Z + (size_t)row * 1024)[t] = o;
}

__global__ void pairs_kernel(const u16* __restrict__ Z, float* __restrict__ dots)
{
  int gt = (int)blockIdx.x * 256 + (int)threadIdx.x;
  int wid = gt >> 6;
  if (wid >= 2046) return;
  int lane = gt & 63;
  int tensor = wid / 1023, tl = wid % 1023 + 1;
  const u16* ra = Z + ((size_t)tensor * 1024 + tl) * 1024;
  const u16* rb = ra - 1024;
  float s = 0.0f;
#pragma unroll
  for (int i = 0; i < 2; ++i) {
    short8 a = *reinterpret_cast<const short8*>(ra + lane * 16 + i * 8);
    short8 b = *reinterpret_cast<const short8*>(rb + lane * 16 + i * 8);
#pragma unroll
    for (int j = 0; j < 8; ++j) s += bf2f((u16)a[j]) * bf2f((u16)b[j]);
  }
#pragma unroll
  for (int d = 1; d < 64; d <<= 1) s += __shfl_xor(s, d);
  if (lane == 0) atomicAdd(dots, s);
}

__global__ void finalize_kernel(const float* __restrict__ S,
                                const float* __restrict__ dots,
                                float* __restrict__ out_loss)
{
  const int t = (int)threadIdx.x;  // 256
  float acc = 0.0f;
  for (int i = t; i < 2048; i += 256) {
    int tl = i & 1023;
    float w = (tl == 0 || tl == 1023) ? 1.0f : 2.0f;
    acc += w * logf(S[i] - 22026.465794806718f);
  }
  __shared__ float red[256];
  red[t] = acc;
  __syncthreads();
  for (int s2 = 128; s2 > 0; s2 >>= 1) {
    if (t < s2) red[t] += red[t + s2];
    __syncthreads();
  }
  if (t == 0) out_loss[0] = (red[0] - 20.0f * dots[0]) / 4092.0f;
}

extern "C" void kernel_launch(void* const* d_in, const int* in_sizes, int n_in,
                              void* d_out, int out_size, void* d_ws, size_t ws_size,
                              hipStream_t stream)
{
  const float* h1 = (const float*)d_in[0];
  const float* h2 = (const float*)d_in[1];
  const float* W1 = (const float*)d_in[2];
  const float* b1 = (const float*)d_in[3];
  const float* W2 = (const float*)d_in[4];
  const float* b2 = (const float*)d_in[5];
  float* out = (float*)d_out;

  char* ws = (char*)d_ws;
  u16*   Xb   = (u16*)ws;                      // 33,554,432 B
  u16*   Y1b  = (u16*)(ws + 33554432);         // 33,554,432 B
  u16*   W1t  = (u16*)(ws + 67108864);         //  2,097,152 B
  u16*   W2t  = (u16*)(ws + 69206016);         //  2,097,152 B
  u16*   Zb   = (u16*)(ws + 71303168);         //  4,194,304 B
  float* S    = (float*)(ws + 75497472);       //      8,192 B
  float* dots = (float*)(ws + 75505664);       //          4 B

  hipMemsetAsync(S, 0, 8192 + 64, stream);

  convert_x<<<16384, 256, 0, stream>>>(h1, h2, Xb);
  transpose_w<<<1024, 256, 0, stream>>>(W1, W1t);
  transpose_w<<<1024, 256, 0, stream>>>(W2, W2t);

  // layer 1: [16384,1024] @ W1 -> relu -> bf16 (256 blocks, 512 thr)
  gemm_bdir<0><<<256, 512, 0, stream>>>(Xb, W1t, b1, Y1b, nullptr);
  // layer 2: -> relu -> fp32, transposed write into d_out ([b][t][h])
  gemm_bdir<1><<<256, 512, 0, stream>>>(Y1b, W2t, b2, nullptr, out);

  // InfoNCE on last batch row
  row_normalize<<<2048, 256, 0, stream>>>(out, Zb);
  pairs_kernel<<<512, 256, 0, stream>>>(Zb, dots);
  sim_kernel<<<256, 256, 0, stream>>>(Zb, S);
  finalize_kernel<<<1, 256, 0, stream>>>(S, dots, out + 16777216);
}

// Round 7
// 143.000 us; speedup vs baseline: 1.4395x; 1.4395x over previous
//
#include <hip/hip_runtime.h>
#include <cstdint>
#include <cstddef>

using u16 = unsigned short;
typedef short short8 __attribute__((ext_vector_type(8)));
typedef __bf16 bf16x8 __attribute__((ext_vector_type(8)));
typedef float f32x4 __attribute__((ext_vector_type(4)));
typedef u16 u16x4 __attribute__((ext_vector_type(4)));

__device__ __forceinline__ u16 f2bf(float f) {
  union { float f; uint32_t u; } v; v.f = f;
  uint32_t r = v.u + 0x7FFF + ((v.u >> 16) & 1);
  return (u16)(r >> 16);
}
__device__ __forceinline__ float bf2f(u16 b) {
  union { uint32_t u; float f; } v; v.u = ((uint32_t)b) << 16;
  return v.f;
}

__device__ __forceinline__ void gload16(const u16* g, u16* l) {
  __builtin_amdgcn_global_load_lds(
      (const __attribute__((address_space(1))) void*)g,
      (__attribute__((address_space(3))) void*)l, 16, 0, 0);
}

// =====================================================================
// 128x128 bf16 GEMM core (R1, proven): 4 waves (2x2), single-buffered
// 2-phase loop, gload_lds staging with XOR-swizzle, 4 blocks/CU.
// Cross-block overlap (m114) is the latency-hiding mechanism.
// =====================================================================
__device__ __forceinline__ void gemm_core_128(
    const u16* __restrict__ A, const u16* __restrict__ B,
    int arow0, int brow0, int K,
    u16* As, u16* Bs, f32x4 (&acc)[4][4])
{
  const int t = (int)threadIdx.x;
  const int lane = t & 63, wv = t >> 6;
  const int wr = wv >> 1, wc = wv & 1;
  const int li = lane & 15, hk = lane >> 4;
  const int sr = t >> 3, sc = t & 7;

#pragma unroll
  for (int m = 0; m < 4; ++m)
#pragma unroll
    for (int n = 0; n < 4; ++n)
#pragma unroll
      for (int j = 0; j < 4; ++j) acc[m][n][j] = 0.0f;

  for (int kt = 0; kt < K; kt += 64) {
#pragma unroll
    for (int i = 0; i < 4; ++i) {
      int row = i * 32 + sr;
      int coff = (sc ^ (row & 7)) << 3;  // pre-swizzled source chunk
      const u16* ga = A + (size_t)(arow0 + row) * K + kt + coff;
      const u16* gb = B + (size_t)(brow0 + row) * K + kt + coff;
      u16* la = As + i * 2048 + wv * 512;  // wave-uniform base; HW adds lane*16B
      u16* lb = Bs + i * 2048 + wv * 512;
      gload16(ga, la);
      gload16(gb, lb);
    }
    __syncthreads();
#pragma unroll
    for (int kk = 0; kk < 2; ++kk) {
      short8 av[4], bv[4];
#pragma unroll
      for (int m = 0; m < 4; ++m) {
        int ra = wr * 64 + m * 16 + li;
        int ca = ((kk << 2) + hk) ^ (ra & 7);
        av[m] = *reinterpret_cast<const short8*>(As + ra * 64 + ca * 8);
      }
#pragma unroll
      for (int n = 0; n < 4; ++n) {
        int rb = wc * 64 + n * 16 + li;
        int cb = ((kk << 2) + hk) ^ (rb & 7);
        bv[n] = *reinterpret_cast<const short8*>(Bs + rb * 64 + cb * 8);
      }
#pragma unroll
      for (int m = 0; m < 4; ++m)
#pragma unroll
        for (int n = 0; n < 4; ++n)
          acc[m][n] = __builtin_amdgcn_mfma_f32_16x16x32_bf16(
              __builtin_bit_cast(bf16x8, av[m]),
              __builtin_bit_cast(bf16x8, bv[n]),
              acc[m][n], 0, 0, 0);
    }
    __syncthreads();
  }
}

// ---------------- MLP GEMM: relu(A@W + b) ----------------
// R7: + bijective XCD swizzle (grid 1024 = 8 XCDs x 128): each XCD owns
// 16 consecutive bm x all 8 bn -> A-panels (16 x 256KB = 4MB) L2-resident,
// A fetched from HBM ~once. EPI==1 writes fp32 transposed to d_out.
template <int EPI>
__global__ __launch_bounds__(256) void gemm_mlp(
    const u16* __restrict__ A, const u16* __restrict__ Bt,
    const float* __restrict__ bias,
    u16* __restrict__ Cb, float* __restrict__ Cf, int N, int K)
{
  __shared__ alignas(16) u16 As[128 * 64];
  __shared__ alignas(16) u16 Bs[128 * 64];
  const int nbn = N >> 7;
  const int orig = (int)blockIdx.x;
  const int cpx = (int)gridDim.x >> 3;              // 128
  const int swz = (orig & 7) * cpx + (orig >> 3);   // bijective (1024 % 8 == 0)
  const int bm = swz / nbn, bn = swz % nbn;
  f32x4 acc[4][4];
  gemm_core_128(A, Bt, bm * 128, bn * 128, K, As, Bs, acc);

  const int t = (int)threadIdx.x;
  const int lane = t & 63, wv = t >> 6;
  const int wr = wv >> 1, wc = wv & 1;
  const int li = lane & 15, hk = lane >> 4;

#pragma unroll
  for (int m = 0; m < 4; ++m) {
#pragma unroll
    for (int n = 0; n < 4; ++n) {
      int gcol = bn * 128 + wc * 64 + n * 16 + li;
      float bv = bias[gcol];
#pragma unroll
      for (int j = 0; j < 4; ++j) {
        int grow = bm * 128 + wr * 64 + m * 16 + hk * 4 + j;
        float v = fmaxf(acc[m][n][j] + bv, 0.0f);
        if (EPI == 0) {
          Cb[(size_t)grow * N + gcol] = f2bf(v);
        } else {
          int tensor = grow >> 13, rr = grow & 8191;
          int tt = rr >> 3, bb = rr & 7;
          Cf[(size_t)tensor * 8388608 + (size_t)bb * 1048576 +
             (size_t)tt * 1024 + gcol] = v;
        }
      }
    }
  }
}

// ---------------- fused prep: convert_x + transpose W1/W2 + zero S ----------------
__global__ void prep_kernel(const float* __restrict__ h1,
                            const float* __restrict__ h2,
                            const float* __restrict__ W1,
                            const float* __restrict__ W2,
                            u16* __restrict__ Xb,
                            u16* __restrict__ W1t,
                            u16* __restrict__ W2t,
                            float* __restrict__ S)
{
  __shared__ float tile[32][33];
  int bid = (int)blockIdx.x;
  if (bid < 16384) {
    // convert h1|h2 (f32) -> Xb (bf16), 4 elems/thread
    size_t i4 = ((size_t)bid * 256 + threadIdx.x) * 4;
    const float* src = (i4 < 8388608) ? (h1 + i4) : (h2 + (i4 - 8388608));
    float4 v = *reinterpret_cast<const float4*>(src);
    u16x4 o;
    o[0] = f2bf(v.x); o[1] = f2bf(v.y); o[2] = f2bf(v.z); o[3] = f2bf(v.w);
    *reinterpret_cast<u16x4*>(Xb + i4) = o;
    return;
  }
  bid -= 16384;
  const float* W;
  u16* Wt;
  if (bid < 1024) {
    W = W1; Wt = W1t;
  } else if (bid < 2048) {
    W = W2; Wt = W2t; bid -= 1024;
  } else {
    // zero S (2048 floats) + dots (at S+2048) + pad
    for (int i = (int)threadIdx.x; i < 2064; i += 256) S[i] = 0.0f;
    return;
  }
  const int bx = bid & 31, by = bid >> 5;
  const int tx = (int)threadIdx.x & 31, ty = (int)threadIdx.x >> 5;
#pragma unroll
  for (int i = 0; i < 4; ++i)
    tile[ty + i * 8][tx] = W[(size_t)(by * 32 + ty + i * 8) * 1024 + bx * 32 + tx];
  __syncthreads();
#pragma unroll
  for (int i = 0; i < 4; ++i)
    Wt[(size_t)(bx * 32 + ty + i * 8) * 1024 + by * 32 + tx] =
        f2bf(tile[tx][ty + i * 8]);
}

// ---------------- similarity GEMM (+ fused pairs reduction) ----------------
// bid < 256: S[m] += sum_col w[col]*exp(10*G[m][col]) over the 2048x2048 Gram.
// bid >= 256 (32 blocks = 128 waves): dots += sum_t Z[t].Z[t-1] per tensor.
__global__ __launch_bounds__(256) void sim_kernel(const u16* __restrict__ Z,
                                                  float* __restrict__ S,
                                                  float* __restrict__ dots)
{
  __shared__ alignas(16) u16 As[128 * 64];
  __shared__ alignas(16) u16 Bs[128 * 64];
  if ((int)blockIdx.x >= 256) {
    const int wv4 = ((int)blockIdx.x - 256) * 4 + ((int)threadIdx.x >> 6);
    const int lane = (int)threadIdx.x & 63;
    float s = 0.0f;
    for (int wid = wv4; wid < 2046; wid += 128) {
      int tensor = wid / 1023, tl = wid % 1023 + 1;
      const u16* ra = Z + ((size_t)tensor * 1024 + tl) * 1024;
      const u16* rb = ra - 1024;
#pragma unroll
      for (int i = 0; i < 2; ++i) {
        short8 a = *reinterpret_cast<const short8*>(ra + lane * 16 + i * 8);
        short8 b = *reinterpret_cast<const short8*>(rb + lane * 16 + i * 8);
#pragma unroll
        for (int j = 0; j < 8; ++j) s += bf2f((u16)a[j]) * bf2f((u16)b[j]);
      }
    }
#pragma unroll
    for (int d = 1; d < 64; d <<= 1) s += __shfl_xor(s, d);
    if (lane == 0) atomicAdd(dots, s);
    return;
  }
  const int bm = (int)blockIdx.x / 16, bn = (int)blockIdx.x % 16;
  f32x4 acc[4][4];
  gemm_core_128(Z, Z, bm * 128, bn * 128, 1024, As, Bs, acc);

  const int t = (int)threadIdx.x;
  const int lane = t & 63, wv = t >> 6;
  const int wr = wv >> 1, wc = wv & 1;
  const int li = lane & 15, hk = lane >> 4;

#pragma unroll
  for (int m = 0; m < 4; ++m) {
#pragma unroll
    for (int j = 0; j < 4; ++j) {
      int grow = bm * 128 + wr * 64 + m * 16 + hk * 4 + j;
      float s = 0.0f;
#pragma unroll
      for (int n = 0; n < 4; ++n) {
        int gcol = bn * 128 + wc * 64 + n * 16 + li;
        float logit = (grow == gcol) ? 10.0f : acc[m][n][j] * 10.0f;
        float w = (gcol == 0 || gcol == 1023 || gcol == 1024 || gcol == 2047)
                      ? 1.0f : 2.0f;
        s += w * expf(logit);
      }
      s += __shfl_xor(s, 1); s += __shfl_xor(s, 2);
      s += __shfl_xor(s, 4); s += __shfl_xor(s, 8);
      if (li == 0) atomicAdd(&S[grow], s);
    }
  }
}

__global__ void row_normalize(const float* __restrict__ out, u16* __restrict__ Z)
{
  const int row = (int)blockIdx.x;   // 0..2047
  const int t = (int)threadIdx.x;    // 256
  const float* src = out + ((row < 1024)
      ? ((size_t)7 * 1048576 + (size_t)row * 1024)
      : ((size_t)8388608 + (size_t)7 * 1048576 + (size_t)(row - 1024) * 1024));
  float4 v = reinterpret_cast<const float4*>(src)[t];
  float ss = v.x * v.x + v.y * v.y + v.z * v.z + v.w * v.w;
#pragma unroll
  for (int d = 1; d < 64; d <<= 1) ss += __shfl_xor(ss, d);
  __shared__ float red[4];
  if ((t & 63) == 0) red[t >> 6] = ss;
  __syncthreads();
  float tot = red[0] + red[1] + red[2] + red[3];
  float inv = 1.0f / fmaxf(sqrtf(tot), 1e-12f);
  u16x4 o;
  o[0] = f2bf(v.x * inv); o[1] = f2bf(v.y * inv);
  o[2] = f2bf(v.z * inv); o[3] = f2bf(v.w * inv);
  reinterpret_cast<u16x4*>(Z + (size_t)row * 1024)[t] = o;
}

__global__ void finalize_kernel(const float* __restrict__ S,
                                const float* __restrict__ dots,
                                float* __restrict__ out_loss)
{
  const int t = (int)threadIdx.x;  // 256
  float acc = 0.0f;
  for (int i = t; i < 2048; i += 256) {
    int tl = i & 1023;
    float w = (tl == 0 || tl == 1023) ? 1.0f : 2.0f;
    acc += w * logf(S[i] - 22026.465794806718f);
  }
  __shared__ float red[256];
  red[t] = acc;
  __syncthreads();
  for (int s2 = 128; s2 > 0; s2 >>= 1) {
    if (t < s2) red[t] += red[t + s2];
    __syncthreads();
  }
  if (t == 0) out_loss[0] = (red[0] - 20.0f * dots[0]) / 4092.0f;
}

extern "C" void kernel_launch(void* const* d_in, const int* in_sizes, int n_in,
                              void* d_out, int out_size, void* d_ws, size_t ws_size,
                              hipStream_t stream)
{
  const float* h1 = (const float*)d_in[0];
  const float* h2 = (const float*)d_in[1];
  const float* W1 = (const float*)d_in[2];
  const float* b1 = (const float*)d_in[3];
  const float* W2 = (const float*)d_in[4];
  const float* b2 = (const float*)d_in[5];
  float* out = (float*)d_out;

  char* ws = (char*)d_ws;
  u16*   Xb   = (u16*)ws;                      // 33,554,432 B
  u16*   Y1b  = (u16*)(ws + 33554432);         // 33,554,432 B
  u16*   W1t  = (u16*)(ws + 67108864);         //  2,097,152 B
  u16*   W2t  = (u16*)(ws + 69206016);         //  2,097,152 B
  u16*   Zb   = (u16*)(ws + 71303168);         //  4,194,304 B
  float* S    = (float*)(ws + 75497472);       //      8,192 B (+dots at S[2048])
  float* dots = S + 2048;

  // fused: convert_x (16384 blocks) + transpose W1/W2 (2048) + zero S (1)
  prep_kernel<<<18433, 256, 0, stream>>>(h1, h2, W1, W2, Xb, W1t, W2t, S);

  // layer 1: [16384,1024] @ W1 -> relu -> bf16
  gemm_mlp<0><<<1024, 256, 0, stream>>>(Xb, W1t, b1, Y1b, nullptr, 1024, 1024);
  // layer 2: -> relu -> fp32, transposed write into d_out ([b][t][h])
  gemm_mlp<1><<<1024, 256, 0, stream>>>(Y1b, W2t, b2, nullptr, out, 1024, 1024);

  // InfoNCE on last batch row
  row_normalize<<<2048, 256, 0, stream>>>(out, Zb);
  sim_kernel<<<288, 256, 0, stream>>>(Zb, S, dots);   // + fused pairs
  finalize_kernel<<<1, 256, 0, stream>>>(S, dots, out + 16777216);
}

// Round 8
// 124.052 us; speedup vs baseline: 1.6594x; 1.1527x over previous
//
#include <hip/hip_runtime.h>
#include <cstdint>
#include <cstddef>

using u16 = unsigned short;
typedef short short8 __attribute__((ext_vector_type(8)));
typedef __bf16 bf16x8 __attribute__((ext_vector_type(8)));
typedef float f32x4 __attribute__((ext_vector_type(4)));
typedef u16 u16x4 __attribute__((ext_vector_type(4)));

__device__ __forceinline__ u16 f2bf(float f) {
  union { float f; uint32_t u; } v; v.f = f;
  uint32_t r = v.u + 0x7FFF + ((v.u >> 16) & 1);
  return (u16)(r >> 16);
}
__device__ __forceinline__ float bf2f(u16 b) {
  union { uint32_t u; float f; } v; v.u = ((uint32_t)b) << 16;
  return v.f;
}

__device__ __forceinline__ void gload16(const u16* g, u16* l) {
  __builtin_amdgcn_global_load_lds(
      (const __attribute__((address_space(1))) void*)g,
      (__attribute__((address_space(3))) void*)l, 16, 0, 0);
}

// =====================================================================
// 256x256 bf16 GEMM, BK=64, 8 waves (2x4), software-pipelined registers
// (R4 structure, best measured: 53.9us). One-phase-ahead ds_reads,
// counted lgkm/vmcnt, 3 barriers per K-tile, XCD-bijective swizzle.
// =====================================================================
#define MFMAQ(M0, N0, AF, BF)                                              \
  {                                                                        \
    _Pragma("unroll") for (int m_ = 0; m_ < 4; ++m_) {                     \
      _Pragma("unroll") for (int n_ = 0; n_ < 2; ++n_) {                   \
        _Pragma("unroll") for (int kk_ = 0; kk_ < 2; ++kk_) {              \
          acc[(M0) + m_][(N0) + n_] =                                      \
              __builtin_amdgcn_mfma_f32_16x16x32_bf16(                     \
                  __builtin_bit_cast(bf16x8, AF[m_][kk_]),                 \
                  __builtin_bit_cast(bf16x8, BF[n_][kk_]),                 \
                  acc[(M0) + m_][(N0) + n_], 0, 0, 0);                     \
        }                                                                  \
      }                                                                    \
    }                                                                      \
  }

template <int EPI>
__global__ __launch_bounds__(512, 2) void gemm_mlp8(
    const u16* __restrict__ A, const u16* __restrict__ Bt,
    const float* __restrict__ bias,
    u16* __restrict__ Cb, float* __restrict__ Cf, int N, int K)
{
  __shared__ alignas(16) u16 lds[65536];  // 128 KiB
  const int NT = K >> 6;

  const int t = (int)threadIdx.x;
  const int lane = t & 63, wid = t >> 6;
  const int wr = wid >> 2, wc = wid & 3;   // 2 x 4 wave grid
  const int li = lane & 15, hk = lane >> 4;

  // bijective XCD swizzle (grid = 256, 8 XCDs, 32 blocks each)
  const int nbn = N >> 8;
  const int orig = (int)blockIdx.x;
  const int cpx = (int)gridDim.x >> 3;
  const int swz = (orig & 7) * cpx + (orig >> 3);
  const int bm = swz / nbn, bn = swz % nbn;
  const int arow0 = bm * 256, brow0 = bn * 256;

  // staging precompute: lane covers row Rl, chunk lane&7; source chunk XOR'd
  const int Rl = lane >> 3;
  const int sc8 = ((lane & 7) ^ Rl) << 3;
  const int wid2 = wid * 2;

  // ds_read swizzled chunk offsets (u16 units); row&7 == li&7 for all frags
  int c8[2];
#pragma unroll
  for (int kk = 0; kk < 2; ++kk) c8[kk] = (((kk << 2) + hk) ^ (li & 7)) << 3;

  const int rB = (wc & 1) * 64;

  f32x4 acc[8][4];
#pragma unroll
  for (int m = 0; m < 8; ++m)
#pragma unroll
    for (int n = 0; n < 4; ++n)
#pragma unroll
      for (int j = 0; j < 4; ++j) acc[m][n][j] = 0.0f;

  auto STAGE = [&](const u16* G, int growbase, int sigma, int ldsoff) {
#pragma unroll
    for (int l = 0; l < 2; ++l) {
      const u16* g = G + (size_t)(growbase + (wid2 + l) * 8 + Rl) * K +
                     sigma * 64 + sc8;
      gload16(g, (u16*)lds + ldsoff + (wid2 + l) * 512);
    }
  };

  short8 aa[4][2], bb01[2][2], bb23[2][2];

  // ---- prologue: stage KT0 + KT1 fully (16 loads); vmcnt(8) => KT0 landed
  STAGE(Bt, brow0 + 0,   0, 32768 + 0);
  STAGE(Bt, brow0 + 128, 0, 32768 + 8192);
  STAGE(A,  arow0 + 0,   0, 0);
  STAGE(A,  arow0 + 128, 0, 8192);
  STAGE(Bt, brow0 + 0,   1, 32768 + 16384);
  STAGE(Bt, brow0 + 128, 1, 32768 + 16384 + 8192);
  STAGE(A,  arow0 + 0,   1, 16384);
  STAGE(A,  arow0 + 128, 1, 16384 + 8192);
  asm volatile("s_waitcnt vmcnt(8)" ::: "memory");
  __builtin_amdgcn_s_barrier();

  {
    const u16* Ab0 = lds + wr * 8192;
    const u16* Bb0 = lds + 32768 + (wc >> 1) * 8192;
#pragma unroll
    for (int m = 0; m < 4; ++m)
#pragma unroll
      for (int kk = 0; kk < 2; ++kk)
        aa[m][kk] = *reinterpret_cast<const short8*>(
            Ab0 + (m * 16 + li) * 64 + c8[kk]);
#pragma unroll
    for (int n = 0; n < 2; ++n)
#pragma unroll
      for (int kk = 0; kk < 2; ++kk)
        bb01[n][kk] = *reinterpret_cast<const short8*>(
            Bb0 + (rB + n * 16 + li) * 64 + c8[kk]);
  }

  for (int tau = 0; tau < NT; ++tau) {
    const int cur = tau & 1, nxt = cur ^ 1;
    const u16* Ab  = lds + cur * 16384 + wr * 8192;
    const u16* Bb  = lds + 32768 + cur * 16384 + (wc >> 1) * 8192;
    const u16* Abn = lds + nxt * 16384 + wr * 8192;
    const u16* Bbn = lds + 32768 + nxt * 16384 + (wc >> 1) * 8192;

    // ---- Q0: read bb23(tau) [consumed Q1]; MFMA(0,0) = aa03 x bb01
#pragma unroll
    for (int n = 0; n < 2; ++n)
#pragma unroll
      for (int kk = 0; kk < 2; ++kk)
        bb23[n][kk] = *reinterpret_cast<const short8*>(
            Bb + (rB + 32 + n * 16 + li) * 64 + c8[kk]);
    asm volatile("s_waitcnt lgkmcnt(4)" ::: "memory");  // aa03,bb01 landed
    __builtin_amdgcn_sched_barrier(0);
    __builtin_amdgcn_s_setprio(1);
    MFMAQ(0, 0, aa, bb01);
    __builtin_amdgcn_s_setprio(0);

    // ---- Q1: MFMA(0,2) = aa03 x bb23; post: read aa47 [consumed Q2]
    asm volatile("s_waitcnt lgkmcnt(0)" ::: "memory");  // bb23 landed
    __builtin_amdgcn_sched_barrier(0);
    __builtin_amdgcn_s_setprio(1);
    MFMAQ(0, 2, aa, bb23);
    __builtin_amdgcn_s_setprio(0);
    __builtin_amdgcn_sched_barrier(0);
#pragma unroll
    for (int m = 0; m < 4; ++m)
#pragma unroll
      for (int kk = 0; kk < 2; ++kk)
        aa[m][kk] = *reinterpret_cast<const short8*>(
            Ab + ((m + 4) * 16 + li) * 64 + c8[kk]);
    __builtin_amdgcn_s_barrier();  // Q1-end (B-stage target freedom)

    // ---- Q2: stage B(tau+2) -> buf[cur]; MFMA(4,2) = aa47 x bb23
    if (tau + 2 < NT) {
      STAGE(Bt, brow0 + 0,   tau + 2, 32768 + cur * 16384);
      STAGE(Bt, brow0 + 128, tau + 2, 32768 + cur * 16384 + 8192);
    }
    asm volatile("s_waitcnt lgkmcnt(0)" ::: "memory");  // aa47 landed
    __builtin_amdgcn_sched_barrier(0);
    __builtin_amdgcn_s_setprio(1);
    MFMAQ(4, 2, aa, bb23);
    __builtin_amdgcn_s_setprio(0);
    __builtin_amdgcn_s_barrier();  // Q2-end (A-stage target freedom)

    // ---- Q3: stage A(tau+2); vmcnt gate; MFMA(4,0); post: reads for tau+1
    if (tau + 2 < NT) {
      STAGE(A, arow0 + 0,   tau + 2, cur * 16384);
      STAGE(A, arow0 + 128, tau + 2, cur * 16384 + 8192);
      asm volatile("s_waitcnt vmcnt(8)" ::: "memory");  // A,B(tau+1) landed
    } else if (tau + 1 < NT) {
      asm volatile("s_waitcnt vmcnt(0)" ::: "memory");
    }
    __builtin_amdgcn_s_barrier();  // Q3-pre (staged-data visibility)
    __builtin_amdgcn_s_setprio(1);
    MFMAQ(4, 0, aa, bb01);
    __builtin_amdgcn_s_setprio(0);
    __builtin_amdgcn_sched_barrier(0);
    if (tau + 1 < NT) {
#pragma unroll
      for (int m = 0; m < 4; ++m)
#pragma unroll
        for (int kk = 0; kk < 2; ++kk)
          aa[m][kk] = *reinterpret_cast<const short8*>(
              Abn + (m * 16 + li) * 64 + c8[kk]);
#pragma unroll
      for (int n = 0; n < 2; ++n)
#pragma unroll
        for (int kk = 0; kk < 2; ++kk)
          bb01[n][kk] = *reinterpret_cast<const short8*>(
              Bbn + (rB + n * 16 + li) * 64 + c8[kk]);
    }
  }

  // ---- epilogue
#pragma unroll
  for (int m = 0; m < 8; ++m) {
#pragma unroll
    for (int n = 0; n < 4; ++n) {
      const int gcol = brow0 + wc * 64 + n * 16 + li;
      const float bv = bias[gcol];
#pragma unroll
      for (int j = 0; j < 4; ++j) {
        const int grow = arow0 + wr * 128 + m * 16 + hk * 4 + j;
        float v = fmaxf(acc[m][n][j] + bv, 0.0f);
        if (EPI == 0) {
          Cb[(size_t)grow * N + gcol] = f2bf(v);
        } else {
          int tensor = grow >> 13, rr = grow & 8191;
          int tt = rr >> 3, b_ = rr & 7;
          Cf[(size_t)tensor * 8388608 + (size_t)b_ * 1048576 +
             (size_t)tt * 1024 + gcol] = v;
        }
      }
    }
  }
}

// =====================================================================
// 128x128 core (round-1, proven) — used by sim_kernel
// =====================================================================
__device__ __forceinline__ void gemm_core_128(
    const u16* __restrict__ A, const u16* __restrict__ B,
    int arow0, int brow0, int K,
    u16* As, u16* Bs, f32x4 (&acc)[4][4])
{
  const int t = (int)threadIdx.x;
  const int lane = t & 63, wv = t >> 6;
  const int wr = wv >> 1, wc = wv & 1;
  const int li = lane & 15, hk = lane >> 4;
  const int sr = t >> 3, sc = t & 7;

#pragma unroll
  for (int m = 0; m < 4; ++m)
#pragma unroll
    for (int n = 0; n < 4; ++n)
#pragma unroll
      for (int j = 0; j < 4; ++j) acc[m][n][j] = 0.0f;

  for (int kt = 0; kt < K; kt += 64) {
#pragma unroll
    for (int i = 0; i < 4; ++i) {
      int row = i * 32 + sr;
      int coff = (sc ^ (row & 7)) << 3;
      const u16* ga = A + (size_t)(arow0 + row) * K + kt + coff;
      const u16* gb = B + (size_t)(brow0 + row) * K + kt + coff;
      u16* la = As + i * 2048 + wv * 512;
      u16* lb = Bs + i * 2048 + wv * 512;
      gload16(ga, la);
      gload16(gb, lb);
    }
    __syncthreads();
#pragma unroll
    for (int kk = 0; kk < 2; ++kk) {
      short8 av[4], bv[4];
#pragma unroll
      for (int m = 0; m < 4; ++m) {
        int ra = wr * 64 + m * 16 + li;
        int ca = ((kk << 2) + hk) ^ (ra & 7);
        av[m] = *reinterpret_cast<const short8*>(As + ra * 64 + ca * 8);
      }
#pragma unroll
      for (int n = 0; n < 4; ++n) {
        int rb = wc * 64 + n * 16 + li;
        int cb = ((kk << 2) + hk) ^ (rb & 7);
        bv[n] = *reinterpret_cast<const short8*>(Bs + rb * 64 + cb * 8);
      }
#pragma unroll
      for (int m = 0; m < 4; ++m)
#pragma unroll
        for (int n = 0; n < 4; ++n)
          acc[m][n] = __builtin_amdgcn_mfma_f32_16x16x32_bf16(
              __builtin_bit_cast(bf16x8, av[m]),
              __builtin_bit_cast(bf16x8, bv[n]),
              acc[m][n], 0, 0, 0);
    }
    __syncthreads();
  }
}

// ---------------- fused prep: convert_x + transpose W1/W2 + zero S ----------------
__global__ void prep_kernel(const float* __restrict__ h1,
                            const float* __restrict__ h2,
                            const float* __restrict__ W1,
                            const float* __restrict__ W2,
                            u16* __restrict__ Xb,
                            u16* __restrict__ W1t,
                            u16* __restrict__ W2t,
                            float* __restrict__ S)
{
  __shared__ float tile[32][33];
  int bid = (int)blockIdx.x;
  if (bid < 16384) {
    size_t i4 = ((size_t)bid * 256 + threadIdx.x) * 4;
    const float* src = (i4 < 8388608) ? (h1 + i4) : (h2 + (i4 - 8388608));
    float4 v = *reinterpret_cast<const float4*>(src);
    u16x4 o;
    o[0] = f2bf(v.x); o[1] = f2bf(v.y); o[2] = f2bf(v.z); o[3] = f2bf(v.w);
    *reinterpret_cast<u16x4*>(Xb + i4) = o;
    return;
  }
  bid -= 16384;
  const float* W;
  u16* Wt;
  if (bid < 1024) {
    W = W1; Wt = W1t;
  } else if (bid < 2048) {
    W = W2; Wt = W2t; bid -= 1024;
  } else {
    for (int i = (int)threadIdx.x; i < 2064; i += 256) S[i] = 0.0f;
    return;
  }
  const int bx = bid & 31, by = bid >> 5;
  const int tx = (int)threadIdx.x & 31, ty = (int)threadIdx.x >> 5;
#pragma unroll
  for (int i = 0; i < 4; ++i)
    tile[ty + i * 8][tx] = W[(size_t)(by * 32 + ty + i * 8) * 1024 + bx * 32 + tx];
  __syncthreads();
#pragma unroll
  for (int i = 0; i < 4; ++i)
    Wt[(size_t)(bx * 32 + ty + i * 8) * 1024 + by * 32 + tx] =
        f2bf(tile[tx][ty + i * 8]);
}

// ---------------- similarity GEMM (+ fused pairs reduction) ----------------
__global__ __launch_bounds__(256) void sim_kernel(const u16* __restrict__ Z,
                                                  float* __restrict__ S,
                                                  float* __restrict__ dots)
{
  __shared__ alignas(16) u16 As[128 * 64];
  __shared__ alignas(16) u16 Bs[128 * 64];
  if ((int)blockIdx.x >= 256) {
    const int wv4 = ((int)blockIdx.x - 256) * 4 + ((int)threadIdx.x >> 6);
    const int lane = (int)threadIdx.x & 63;
    float s = 0.0f;
    for (int wid = wv4; wid < 2046; wid += 128) {
      int tensor = wid / 1023, tl = wid % 1023 + 1;
      const u16* ra = Z + ((size_t)tensor * 1024 + tl) * 1024;
      const u16* rb = ra - 1024;
#pragma unroll
      for (int i = 0; i < 2; ++i) {
        short8 a = *reinterpret_cast<const short8*>(ra + lane * 16 + i * 8);
        short8 b = *reinterpret_cast<const short8*>(rb + lane * 16 + i * 8);
#pragma unroll
        for (int j = 0; j < 8; ++j) s += bf2f((u16)a[j]) * bf2f((u16)b[j]);
      }
    }
#pragma unroll
    for (int d = 1; d < 64; d <<= 1) s += __shfl_xor(s, d);
    if (lane == 0) atomicAdd(dots, s);
    return;
  }
  const int bm = (int)blockIdx.x / 16, bn = (int)blockIdx.x % 16;
  f32x4 acc[4][4];
  gemm_core_128(Z, Z, bm * 128, bn * 128, 1024, As, Bs, acc);

  const int t = (int)threadIdx.x;
  const int lane = t & 63, wv = t >> 6;
  const int wr = wv >> 1, wc = wv & 1;
  const int li = lane & 15, hk = lane >> 4;

#pragma unroll
  for (int m = 0; m < 4; ++m) {
#pragma unroll
    for (int j = 0; j < 4; ++j) {
      int grow = bm * 128 + wr * 64 + m * 16 + hk * 4 + j;
      float s = 0.0f;
#pragma unroll
      for (int n = 0; n < 4; ++n) {
        int gcol = bn * 128 + wc * 64 + n * 16 + li;
        float logit = (grow == gcol) ? 10.0f : acc[m][n][j] * 10.0f;
        float w = (gcol == 0 || gcol == 1023 || gcol == 1024 || gcol == 2047)
                      ? 1.0f : 2.0f;
        s += w * expf(logit);
      }
      s += __shfl_xor(s, 1); s += __shfl_xor(s, 2);
      s += __shfl_xor(s, 4); s += __shfl_xor(s, 8);
      if (li == 0) atomicAdd(&S[grow], s);
    }
  }
}

__global__ void row_normalize(const float* __restrict__ out, u16* __restrict__ Z)
{
  const int row = (int)blockIdx.x;   // 0..2047
  const int t = (int)threadIdx.x;    // 256
  const float* src = out + ((row < 1024)
      ? ((size_t)7 * 1048576 + (size_t)row * 1024)
      : ((size_t)8388608 + (size_t)7 * 1048576 + (size_t)(row - 1024) * 1024));
  float4 v = reinterpret_cast<const float4*>(src)[t];
  float ss = v.x * v.x + v.y * v.y + v.z * v.z + v.w * v.w;
#pragma unroll
  for (int d = 1; d < 64; d <<= 1) ss += __shfl_xor(ss, d);
  __shared__ float red[4];
  if ((t & 63) == 0) red[t >> 6] = ss;
  __syncthreads();
  float tot = red[0] + red[1] + red[2] + red[3];
  float inv = 1.0f / fmaxf(sqrtf(tot), 1e-12f);
  u16x4 o;
  o[0] = f2bf(v.x * inv); o[1] = f2bf(v.y * inv);
  o[2] = f2bf(v.z * inv); o[3] = f2bf(v.w * inv);
  reinterpret_cast<u16x4*>(Z + (size_t)row * 1024)[t] = o;
}

__global__ void finalize_kernel(const float* __restrict__ S,
                                const float* __restrict__ dots,
                                float* __restrict__ out_loss)
{
  const int t = (int)threadIdx.x;  // 256
  float acc = 0.0f;
  for (int i = t; i < 2048; i += 256) {
    int tl = i & 1023;
    float w = (tl == 0 || tl == 1023) ? 1.0f : 2.0f;
    acc += w * logf(S[i] - 22026.465794806718f);
  }
  __shared__ float red[256];
  red[t] = acc;
  __syncthreads();
  for (int s2 = 128; s2 > 0; s2 >>= 1) {
    if (t < s2) red[t] += red[t + s2];
    __syncthreads();
  }
  if (t == 0) out_loss[0] = (red[0] - 20.0f * dots[0]) / 4092.0f;
}

extern "C" void kernel_launch(void* const* d_in, const int* in_sizes, int n_in,
                              void* d_out, int out_size, void* d_ws, size_t ws_size,
                              hipStream_t stream)
{
  const float* h1 = (const float*)d_in[0];
  const float* h2 = (const float*)d_in[1];
  const float* W1 = (const float*)d_in[2];
  const float* b1 = (const float*)d_in[3];
  const float* W2 = (const float*)d_in[4];
  const float* b2 = (const float*)d_in[5];
  float* out = (float*)d_out;

  char* ws = (char*)d_ws;
  u16*   Xb   = (u16*)ws;                      // 33,554,432 B
  u16*   Y1b  = (u16*)(ws + 33554432);         // 33,554,432 B
  u16*   W1t  = (u16*)(ws + 67108864);         //  2,097,152 B
  u16*   W2t  = (u16*)(ws + 69206016);         //  2,097,152 B
  u16*   Zb   = (u16*)(ws + 71303168);         //  4,194,304 B
  float* S    = (float*)(ws + 75497472);       //      8,192 B (+dots at S[2048])
  float* dots = S + 2048;

  // fused: convert_x (16384 blocks) + transpose W1/W2 (2048) + zero S (1)
  prep_kernel<<<18433, 256, 0, stream>>>(h1, h2, W1, W2, Xb, W1t, W2t, S);

  // layer 1: [16384,1024] @ W1 -> relu -> bf16 (256 blocks, 512 thr)
  gemm_mlp8<0><<<256, 512, 0, stream>>>(Xb, W1t, b1, Y1b, nullptr, 1024, 1024);
  // layer 2: -> relu -> fp32, transposed write into d_out ([b][t][h])
  gemm_mlp8<1><<<256, 512, 0, stream>>>(Y1b, W2t, b2, nullptr, out, 1024, 1024);

  // InfoNCE on last batch row
  row_normalize<<<2048, 256, 0, stream>>>(out, Zb);
  sim_kernel<<<288, 256, 0, stream>>>(Zb, S, dots);   // + fused pairs
  finalize_kernel<<<1, 256, 0, stream>>>(S, dots, out + 16777216);
}

// Round 9
// 95.764 us; speedup vs baseline: 2.1496x; 1.2954x over previous
//
#include <hip/hip_runtime.h>
#include <cstdint>
#include <cstddef>

using u16 = unsigned short;
using u8  = unsigned char;
typedef short short8 __attribute__((ext_vector_type(8)));
typedef __bf16 bf16x8 __attribute__((ext_vector_type(8)));
typedef float f32x4 __attribute__((ext_vector_type(4)));
typedef u16 u16x4 __attribute__((ext_vector_type(4)));
typedef int i32x4 __attribute__((ext_vector_type(4)));
typedef int i32x8 __attribute__((ext_vector_type(8)));

__device__ __forceinline__ u16 f2bf(float f) {
  union { float f; uint32_t u; } v; v.f = f;
  uint32_t r = v.u + 0x7FFF + ((v.u >> 16) & 1);
  return (u16)(r >> 16);
}
__device__ __forceinline__ float bf2f(u16 b) {
  union { uint32_t u; float f; } v; v.u = ((uint32_t)b) << 16;
  return v.f;
}
__device__ __forceinline__ u8 f2fp8(float f) {
  return (u8)(__builtin_amdgcn_cvt_pk_fp8_f32(f, f, 0, 0) & 0xFF);
}

__device__ __forceinline__ void gload16(const void* g, void* l) {
  __builtin_amdgcn_global_load_lds(
      (const __attribute__((address_space(1))) void*)g,
      (__attribute__((address_space(3))) void*)l, 16, 0, 0);
}

// =====================================================================
// R9: 256x256 MX-fp8 GEMM, BK=128 (bytes), NT=8, 8 waves (2x4), R8's
// proven pipeline skeleton (one-phase-ahead reads, counted lgkm/vmcnt,
// 3 barriers/tile, XCD swizzle). MFMA = mfma_scale_f32_16x16x128_f8f6f4
// with unit scales (127 = 2^0). A,B staged with IDENTICAL column
// permutation -> internal k-order cancels (layout-agnostic).
// Inputs pre-scaled: X*8, W*64 -> epilogue acc/512.
// =====================================================================
#define MFMAQ8(M0, N0, AF, BF)                                             \
  {                                                                        \
    _Pragma("unroll") for (int m_ = 0; m_ < 4; ++m_) {                     \
      _Pragma("unroll") for (int n_ = 0; n_ < 2; ++n_) {                   \
        acc[(M0) + m_][(N0) + n_] =                                        \
            __builtin_amdgcn_mfma_scale_f32_16x16x128_f8f6f4(              \
                AF[m_], BF[n_], acc[(M0) + m_][(N0) + n_],                 \
                0, 0, 0, 127, 0, 127);                                     \
      }                                                                    \
    }                                                                      \
  }

template <int EPI>
__global__ __launch_bounds__(512, 2) void gemm_fp8(
    const u8* __restrict__ A, const u8* __restrict__ Bt,
    const float* __restrict__ bias,
    u8* __restrict__ C8, float* __restrict__ Cf)
{
  constexpr int Kb = 1024, N = 1024, NT = 8;
  __shared__ alignas(16) u8 lds[131072];  // A: 2x32KB @0, B: 2x32KB @65536

  const int t = (int)threadIdx.x;
  const int lane = t & 63, wid = t >> 6;
  const int wr = wid >> 2, wc = wid & 3;   // 2 x 4 wave grid
  const int li = lane & 15, hk = lane >> 4;

  // bijective XCD swizzle (grid = 256, 8 XCDs, 32 blocks each)
  const int orig = (int)blockIdx.x;
  const int cpx = (int)gridDim.x >> 3;
  const int swz = (orig & 7) * cpx + (orig >> 3);
  const int bm = swz >> 2, bn = swz & 3;   // nbn = 4
  const int arow0 = bm * 256, brow0 = bn * 256;

  // staging: lane covers row Rl (of 8-row group), 16B chunk lane&7, XOR'd
  const int Rl = lane >> 3;
  const int sc16 = ((lane & 7) ^ Rl) << 4;   // source byte offset
  const int wid2 = wid * 2;

  // ds_read swizzled chunk byte-offsets (16B chunks, 8 per 128B row)
  const int c0b = (((hk << 1) + 0) ^ (li & 7)) << 4;
  const int c1b = (((hk << 1) + 1) ^ (li & 7)) << 4;

  f32x4 acc[8][4];
#pragma unroll
  for (int m = 0; m < 8; ++m)
#pragma unroll
    for (int n = 0; n < 4; ++n)
#pragma unroll
      for (int j = 0; j < 4; ++j) acc[m][n][j] = 0.0f;

  // stage one 128-row half (16KB): 2 gload16/thread
  auto STAGE = [&](const u8* G, int growbase, int tau, int ldsoff) {
#pragma unroll
    for (int l = 0; l < 2; ++l) {
      const u8* g = G + (size_t)(growbase + (wid2 + l) * 8 + Rl) * Kb +
                    tau * 128 + sc16;
      gload16(g, lds + ldsoff + (wid2 + l) * 1024);
    }
  };
  auto RD = [&](const u8* base, int row) -> i32x8 {
    const u8* p = base + row * 128;
    i32x4 lo = *reinterpret_cast<const i32x4*>(p + c0b);
    i32x4 hi = *reinterpret_cast<const i32x4*>(p + c1b);
    i32x8 r;
    r[0] = lo[0]; r[1] = lo[1]; r[2] = lo[2]; r[3] = lo[3];
    r[4] = hi[0]; r[5] = hi[1]; r[6] = hi[2]; r[7] = hi[3];
    return r;
  };

  i32x8 aa[4], bb01[2], bb23[2];

  // ---- prologue: stage KT0 + KT1 (16 loads); vmcnt(8) => KT0 landed
  STAGE(Bt, brow0 + 0,   0, 65536 + 0);
  STAGE(Bt, brow0 + 128, 0, 65536 + 16384);
  STAGE(A,  arow0 + 0,   0, 0);
  STAGE(A,  arow0 + 128, 0, 16384);
  STAGE(Bt, brow0 + 0,   1, 65536 + 32768);
  STAGE(Bt, brow0 + 128, 1, 65536 + 32768 + 16384);
  STAGE(A,  arow0 + 0,   1, 32768);
  STAGE(A,  arow0 + 128, 1, 32768 + 16384);
  asm volatile("s_waitcnt vmcnt(8)" ::: "memory");
  __builtin_amdgcn_s_barrier();

  {
    const u8* Ab0 = lds + wr * 16384;          // wave's 128 A-rows
    const u8* Bb0 = lds + 65536 + wc * 8192;   // wave's 64 B-rows
#pragma unroll
    for (int m = 0; m < 4; ++m) aa[m] = RD(Ab0, m * 16 + li);
#pragma unroll
    for (int n = 0; n < 2; ++n) bb01[n] = RD(Bb0, n * 16 + li);
  }

  for (int tau = 0; tau < NT; ++tau) {
    const int cur = tau & 1, nxt = cur ^ 1;
    const u8* Ab  = lds + cur * 32768 + wr * 16384;
    const u8* Bb  = lds + 65536 + cur * 32768 + wc * 8192;
    const u8* Abn = lds + nxt * 32768 + wr * 16384;
    const u8* Bbn = lds + 65536 + nxt * 32768 + wc * 8192;

    // ---- Q0: read bb23(tau) [consumed Q1]; MFMA(0,0) = aa03 x bb01
#pragma unroll
    for (int n = 0; n < 2; ++n) bb23[n] = RD(Bb, 32 + n * 16 + li);
    asm volatile("s_waitcnt lgkmcnt(4)" ::: "memory");  // aa03,bb01 landed
    __builtin_amdgcn_sched_barrier(0);
    __builtin_amdgcn_s_setprio(1);
    MFMAQ8(0, 0, aa, bb01);
    __builtin_amdgcn_s_setprio(0);

    // ---- Q1: MFMA(0,2) = aa03 x bb23; post: read aa47 [consumed Q2]
    asm volatile("s_waitcnt lgkmcnt(0)" ::: "memory");  // bb23 landed
    __builtin_amdgcn_sched_barrier(0);
    __builtin_amdgcn_s_setprio(1);
    MFMAQ8(0, 2, aa, bb23);
    __builtin_amdgcn_s_setprio(0);
    __builtin_amdgcn_sched_barrier(0);
#pragma unroll
    for (int m = 0; m < 4; ++m) aa[m] = RD(Ab, (m + 4) * 16 + li);
    __builtin_amdgcn_s_barrier();  // Q1-end (B-stage target freedom)

    // ---- Q2: stage B(tau+2) -> buf[cur]; MFMA(4,2) = aa47 x bb23
    if (tau + 2 < NT) {
      STAGE(Bt, brow0 + 0,   tau + 2, 65536 + cur * 32768);
      STAGE(Bt, brow0 + 128, tau + 2, 65536 + cur * 32768 + 16384);
    }
    asm volatile("s_waitcnt lgkmcnt(0)" ::: "memory");  // aa47 landed
    __builtin_amdgcn_sched_barrier(0);
    __builtin_amdgcn_s_setprio(1);
    MFMAQ8(4, 2, aa, bb23);
    __builtin_amdgcn_s_setprio(0);
    __builtin_amdgcn_s_barrier();  // Q2-end (A-stage target freedom)

    // ---- Q3: stage A(tau+2); vmcnt gate; MFMA(4,0); post: reads for tau+1
    if (tau + 2 < NT) {
      STAGE(A, arow0 + 0,   tau + 2, cur * 32768);
      STAGE(A, arow0 + 128, tau + 2, cur * 32768 + 16384);
      asm volatile("s_waitcnt vmcnt(8)" ::: "memory");  // A,B(tau+1) landed
    } else if (tau + 1 < NT) {
      asm volatile("s_waitcnt vmcnt(0)" ::: "memory");
    }
    __builtin_amdgcn_s_barrier();  // Q3-pre (staged-data visibility)
    __builtin_amdgcn_s_setprio(1);
    MFMAQ8(4, 0, aa, bb01);
    __builtin_amdgcn_s_setprio(0);
    __builtin_amdgcn_sched_barrier(0);
    if (tau + 1 < NT) {
#pragma unroll
      for (int m = 0; m < 4; ++m) aa[m] = RD(Abn, m * 16 + li);
#pragma unroll
      for (int n = 0; n < 2; ++n) bb01[n] = RD(Bbn, n * 16 + li);
    }
  }

  // ---- epilogue: v = acc/512 + bias, relu; EPI0 -> fp8 (x8), EPI1 -> f32
#pragma unroll
  for (int m = 0; m < 8; ++m) {
#pragma unroll
    for (int n = 0; n < 4; ++n) {
      const int gcol = brow0 + wc * 64 + n * 16 + li;
      const float bv = bias[gcol];
#pragma unroll
      for (int j = 0; j < 4; ++j) {
        const int grow = arow0 + wr * 128 + m * 16 + hk * 4 + j;
        float v = fmaxf(acc[m][n][j] * 0.001953125f + bv, 0.0f);
        if (EPI == 0) {
          C8[(size_t)grow * N + gcol] = f2fp8(v * 8.0f);
        } else {
          int tensor = grow >> 13, rr = grow & 8191;
          int tt = rr >> 3, b_ = rr & 7;
          Cf[(size_t)tensor * 8388608 + (size_t)b_ * 1048576 +
             (size_t)tt * 1024 + gcol] = v;
        }
      }
    }
  }
}

// =====================================================================
// 128x128 bf16 core (round-1, proven) — used by sim_kernel
// =====================================================================
__device__ __forceinline__ void gemm_core_128(
    const u16* __restrict__ A, const u16* __restrict__ B,
    int arow0, int brow0, int K,
    u16* As, u16* Bs, f32x4 (&acc)[4][4])
{
  const int t = (int)threadIdx.x;
  const int lane = t & 63, wv = t >> 6;
  const int wr = wv >> 1, wc = wv & 1;
  const int li = lane & 15, hk = lane >> 4;
  const int sr = t >> 3, sc = t & 7;

#pragma unroll
  for (int m = 0; m < 4; ++m)
#pragma unroll
    for (int n = 0; n < 4; ++n)
#pragma unroll
      for (int j = 0; j < 4; ++j) acc[m][n][j] = 0.0f;

  for (int kt = 0; kt < K; kt += 64) {
#pragma unroll
    for (int i = 0; i < 4; ++i) {
      int row = i * 32 + sr;
      int coff = (sc ^ (row & 7)) << 3;
      const u16* ga = A + (size_t)(arow0 + row) * K + kt + coff;
      const u16* gb = B + (size_t)(brow0 + row) * K + kt + coff;
      u16* la = As + i * 2048 + wv * 512;
      u16* lb = Bs + i * 2048 + wv * 512;
      gload16(ga, la);
      gload16(gb, lb);
    }
    __syncthreads();
#pragma unroll
    for (int kk = 0; kk < 2; ++kk) {
      short8 av[4], bv[4];
#pragma unroll
      for (int m = 0; m < 4; ++m) {
        int ra = wr * 64 + m * 16 + li;
        int ca = ((kk << 2) + hk) ^ (ra & 7);
        av[m] = *reinterpret_cast<const short8*>(As + ra * 64 + ca * 8);
      }
#pragma unroll
      for (int n = 0; n < 4; ++n) {
        int rb = wc * 64 + n * 16 + li;
        int cb = ((kk << 2) + hk) ^ (rb & 7);
        bv[n] = *reinterpret_cast<const short8*>(Bs + rb * 64 + cb * 8);
      }
#pragma unroll
      for (int m = 0; m < 4; ++m)
#pragma unroll
        for (int n = 0; n < 4; ++n)
          acc[m][n] = __builtin_amdgcn_mfma_f32_16x16x32_bf16(
              __builtin_bit_cast(bf16x8, av[m]),
              __builtin_bit_cast(bf16x8, bv[n]),
              acc[m][n], 0, 0, 0);
    }
    __syncthreads();
  }
}

// ---------------- fused prep: convert_x(fp8,x8) + transpose W(fp8,x64) + zero S
__global__ void prep_kernel(const float* __restrict__ h1,
                            const float* __restrict__ h2,
                            const float* __restrict__ W1,
                            const float* __restrict__ W2,
                            u8* __restrict__ X8,
                            u8* __restrict__ W1t,
                            u8* __restrict__ W2t,
                            float* __restrict__ S)
{
  __shared__ float tile[32][33];
  int bid = (int)blockIdx.x;
  if (bid < 16384) {
    size_t i4 = ((size_t)bid * 256 + threadIdx.x) * 4;
    const float* src = (i4 < 8388608) ? (h1 + i4) : (h2 + (i4 - 8388608));
    float4 v = *reinterpret_cast<const float4*>(src);
    int lo = __builtin_amdgcn_cvt_pk_fp8_f32(v.x * 8.0f, v.y * 8.0f, 0, 0);
    int all4 = __builtin_amdgcn_cvt_pk_fp8_f32(v.z * 8.0f, v.w * 8.0f, lo, 1);
    *reinterpret_cast<uint32_t*>(X8 + i4) = (uint32_t)all4;
    return;
  }
  bid -= 16384;
  const float* W;
  u8* Wt;
  if (bid < 1024) {
    W = W1; Wt = W1t;
  } else if (bid < 2048) {
    W = W2; Wt = W2t; bid -= 1024;
  } else {
    for (int i = (int)threadIdx.x; i < 2064; i += 256) S[i] = 0.0f;
    return;
  }
  const int bx = bid & 31, by = bid >> 5;
  const int tx = (int)threadIdx.x & 31, ty = (int)threadIdx.x >> 5;
#pragma unroll
  for (int i = 0; i < 4; ++i)
    tile[ty + i * 8][tx] = W[(size_t)(by * 32 + ty + i * 8) * 1024 + bx * 32 + tx];
  __syncthreads();
#pragma unroll
  for (int i = 0; i < 4; ++i)
    Wt[(size_t)(bx * 32 + ty + i * 8) * 1024 + by * 32 + tx] =
        f2fp8(tile[tx][ty + i * 8] * 64.0f);
}

// ---------------- similarity GEMM (+ fused pairs reduction), bf16 ----------------
__global__ __launch_bounds__(256) void sim_kernel(const u16* __restrict__ Z,
                                                  float* __restrict__ S,
                                                  float* __restrict__ dots)
{
  __shared__ alignas(16) u16 As[128 * 64];
  __shared__ alignas(16) u16 Bs[128 * 64];
  if ((int)blockIdx.x >= 256) {
    const int wv4 = ((int)blockIdx.x - 256) * 4 + ((int)threadIdx.x >> 6);
    const int lane = (int)threadIdx.x & 63;
    float s = 0.0f;
    for (int wid = wv4; wid < 2046; wid += 128) {
      int tensor = wid / 1023, tl = wid % 1023 + 1;
      const u16* ra = Z + ((size_t)tensor * 1024 + tl) * 1024;
      const u16* rb = ra - 1024;
#pragma unroll
      for (int i = 0; i < 2; ++i) {
        short8 a = *reinterpret_cast<const short8*>(ra + lane * 16 + i * 8);
        short8 b = *reinterpret_cast<const short8*>(rb + lane * 16 + i * 8);
#pragma unroll
        for (int j = 0; j < 8; ++j) s += bf2f((u16)a[j]) * bf2f((u16)b[j]);
      }
    }
#pragma unroll
    for (int d = 1; d < 64; d <<= 1) s += __shfl_xor(s, d);
    if (lane == 0) atomicAdd(dots, s);
    return;
  }
  const int bm = (int)blockIdx.x / 16, bn = (int)blockIdx.x % 16;
  f32x4 acc[4][4];
  gemm_core_128(Z, Z, bm * 128, bn * 128, 1024, As, Bs, acc);

  const int t = (int)threadIdx.x;
  const int lane = t & 63, wv = t >> 6;
  const int wr = wv >> 1, wc = wv & 1;
  const int li = lane & 15, hk = lane >> 4;

#pragma unroll
  for (int m = 0; m < 4; ++m) {
#pragma unroll
    for (int j = 0; j < 4; ++j) {
      int grow = bm * 128 + wr * 64 + m * 16 + hk * 4 + j;
      float s = 0.0f;
#pragma unroll
      for (int n = 0; n < 4; ++n) {
        int gcol = bn * 128 + wc * 64 + n * 16 + li;
        float logit = (grow == gcol) ? 10.0f : acc[m][n][j] * 10.0f;
        float w = (gcol == 0 || gcol == 1023 || gcol == 1024 || gcol == 2047)
                      ? 1.0f : 2.0f;
        s += w * expf(logit);
      }
      s += __shfl_xor(s, 1); s += __shfl_xor(s, 2);
      s += __shfl_xor(s, 4); s += __shfl_xor(s, 8);
      if (li == 0) atomicAdd(&S[grow], s);
    }
  }
}

__global__ void row_normalize(const float* __restrict__ out, u16* __restrict__ Z)
{
  const int row = (int)blockIdx.x;   // 0..2047
  const int t = (int)threadIdx.x;    // 256
  const float* src = out + ((row < 1024)
      ? ((size_t)7 * 1048576 + (size_t)row * 1024)
      : ((size_t)8388608 + (size_t)7 * 1048576 + (size_t)(row - 1024) * 1024));
  float4 v = reinterpret_cast<const float4*>(src)[t];
  float ss = v.x * v.x + v.y * v.y + v.z * v.z + v.w * v.w;
#pragma unroll
  for (int d = 1; d < 64; d <<= 1) ss += __shfl_xor(ss, d);
  __shared__ float red[4];
  if ((t & 63) == 0) red[t >> 6] = ss;
  __syncthreads();
  float tot = red[0] + red[1] + red[2] + red[3];
  float inv = 1.0f / fmaxf(sqrtf(tot), 1e-12f);
  u16x4 o;
  o[0] = f2bf(v.x * inv); o[1] = f2bf(v.y * inv);
  o[2] = f2bf(v.z * inv); o[3] = f2bf(v.w * inv);
  reinterpret_cast<u16x4*>(Z + (size_t)row * 1024)[t] = o;
}

__global__ void finalize_kernel(const float* __restrict__ S,
                                const float* __restrict__ dots,
                                float* __restrict__ out_loss)
{
  const int t = (int)threadIdx.x;  // 256
  float acc = 0.0f;
  for (int i = t; i < 2048; i += 256) {
    int tl = i & 1023;
    float w = (tl == 0 || tl == 1023) ? 1.0f : 2.0f;
    acc += w * logf(S[i] - 22026.465794806718f);
  }
  __shared__ float red[256];
  red[t] = acc;
  __syncthreads();
  for (int s2 = 128; s2 > 0; s2 >>= 1) {
    if (t < s2) red[t] += red[t + s2];
    __syncthreads();
  }
  if (t == 0) out_loss[0] = (red[0] - 20.0f * dots[0]) / 4092.0f;
}

extern "C" void kernel_launch(void* const* d_in, const int* in_sizes, int n_in,
                              void* d_out, int out_size, void* d_ws, size_t ws_size,
                              hipStream_t stream)
{
  const float* h1 = (const float*)d_in[0];
  const float* h2 = (const float*)d_in[1];
  const float* W1 = (const float*)d_in[2];
  const float* b1 = (const float*)d_in[3];
  const float* W2 = (const float*)d_in[4];
  const float* b2 = (const float*)d_in[5];
  float* out = (float*)d_out;

  char* ws = (char*)d_ws;
  u8*    X8   = (u8*)ws;                       // 16,777,216 B (fp8, x8)
  u8*    Y18  = (u8*)(ws + 16777216);          // 16,777,216 B (fp8, x8)
  u8*    W1t  = (u8*)(ws + 33554432);          //  1,048,576 B (fp8, x64)
  u8*    W2t  = (u8*)(ws + 34603008);          //  1,048,576 B (fp8, x64)
  u16*   Zb   = (u16*)(ws + 35651584);         //  4,194,304 B (bf16)
  float* S    = (float*)(ws + 39845888);       //      8,192 B (+dots at S[2048])
  float* dots = S + 2048;

  // fused: convert_x (16384 blocks) + transpose W1/W2 (2048) + zero S (1)
  prep_kernel<<<18433, 256, 0, stream>>>(h1, h2, W1, W2, X8, W1t, W2t, S);

  // layer 1: [16384,1024] @ W1 -> relu -> fp8 (256 blocks, 512 thr, MX-fp8)
  gemm_fp8<0><<<256, 512, 0, stream>>>(X8, W1t, b1, Y18, nullptr);
  // layer 2: -> relu -> fp32, transposed write into d_out ([b][t][h])
  gemm_fp8<1><<<256, 512, 0, stream>>>(Y18, W2t, b2, nullptr, out);

  // InfoNCE on last batch row (bf16 path, unchanged)
  row_normalize<<<2048, 256, 0, stream>>>(out, Zb);
  sim_kernel<<<288, 256, 0, stream>>>(Zb, S, dots);   // + fused pairs
  finalize_kernel<<<1, 256, 0, stream>>>(S, dots, out + 16777216);
}